// Round 9
// baseline (24.446 us; speedup 1.0000x reference)
//
#include <hip/hip_runtime.h>
#include <math.h>

// Tropical (min-plus) linear: out[b,o] = min_i(X[b,i] + W[o,i])
// B=1024, I=512, O=512 fp32 in/out. Pure-VALU problem (no min-plus MFMA).
//
// Round-9 == round-8 with the shufflevector constant-index fix.
// FP16 CANDIDATE MATH (threshold 9.06e-2; fp16 error ~5e-3):
//  - Pre-pass kernel converts X,W -> fp16 into d_ws (1.5 MB).
//  - Inner math fully packed: v_pk_add_f16 + v_pk_min_f16
//    => 1.0 VALU inst per candidate (fp32 has no packed min).
//  - Halved bytes: X tile 16b x 512k = 16 KB LDS (staged once via
//    global_load_lds, broadcast ds_read_b128 in-loop); W streamed from L1
//    per-lane coalesced f16x8.
//  - lane = (og[2], k16[4]); acc 8b x 4o half2 per thread; pair-reduce to
//    f32, then 4-step compacting butterfly min over k16; 2 outputs/thread.
//  - Grid 1024 blocks (16 b x 32 o), XCD-swizzled, 4 waves/SIMD.

#define B_SZ  1024
#define O_F   512
#define I_F   512
#define MB    8      // b rows per thread (and per wave)
#define NO    4      // o per thread (wave covers 16 o)
#define NTHR  256
#define XN    (B_SZ * I_F)   // 524288 X elems
#define WN    (O_F * I_F)    // 262144 W elems

typedef __attribute__((ext_vector_type(4))) float    f32x4;
typedef __attribute__((ext_vector_type(8))) _Float16 f16x8;
typedef __attribute__((ext_vector_type(2))) _Float16 h2;

template <int J>
static __device__ __forceinline__ h2 pair_of(f16x8 v) {
  return __builtin_shufflevector(v, v, 2 * J, 2 * J + 1);
}

static __device__ __forceinline__ h2 pkmin(h2 a, h2 b) {
  h2 r;
  asm("v_pk_min_f16 %0, %1, %2" : "=v"(r) : "v"(a), "v"(b));
  return r;
}

// ---- pre-pass: convert X and W to fp16 in ws ----
__global__ __launch_bounds__(NTHR, 8)
void cvt_f16(const float* __restrict__ X, const float* __restrict__ W,
             f16x8* __restrict__ dst) {   // [XN/8] X then [WN/8] W
  const int t = blockIdx.x * NTHR + threadIdx.x;   // < (XN+WN)/8 = 98304
  const f32x4* __restrict__ Xv = reinterpret_cast<const f32x4*>(X);
  const f32x4* __restrict__ Wv = reinterpret_cast<const f32x4*>(W);
  f32x4 a, b;
  if (t < XN / 8) { a = Xv[2 * t];              b = Xv[2 * t + 1]; }
  else            { const int u = t - XN / 8;
                    a = Wv[2 * u];              b = Wv[2 * u + 1]; }
  f16x8 h;
  h[0] = (_Float16)a.x; h[1] = (_Float16)a.y;
  h[2] = (_Float16)a.z; h[3] = (_Float16)a.w;
  h[4] = (_Float16)b.x; h[5] = (_Float16)b.y;
  h[6] = (_Float16)b.z; h[7] = (_Float16)b.w;
  dst[t] = h;
}

// ---- main kernel ----
__global__ __launch_bounds__(NTHR, 4)
void tropical_v9(const f16x8* __restrict__ Xh,   // [B][64] f16x8
                 const f16x8* __restrict__ Wh,   // [O][64] f16x8
                 float* __restrict__ out) {
  __shared__ f16x8 Xs[16 * 64];   // 16 KB: [b(16)][slot(64)] linear

  const int tid  = threadIdx.x;
  const int wv   = tid >> 6;
  const int lane = tid & 63;
  const int k16  = lane & 15;   // slot position within 16-lane group
  const int og   = lane >> 4;   // o subgroup 0..3

  // Block tile: 16 b x 32 o; b varies fastest within an XCD (W-panel L2 reuse).
  const int bid = blockIdx.x;
  const int swz = (bid & 7) * 128 + (bid >> 3);   // bijective, 1024 % 8 == 0
  const int ot  = swz >> 6;                       // 16 o-tiles of 32
  const int bt  = swz & 63;                      // 64 b-tiles of 16
  const int b0b = bt * 16;                        // block b base
  const int o0  = ot * 32 + (wv & 1) * 16;        // wave o base
  const int bw  = (wv >> 1) * MB;                 // wave b offset in tile

  // ---- stage X tile once: 1024 f16x8 slots = 4 rounds x 256 lanes ----
#pragma unroll
  for (int it = 0; it < 4; ++it) {
    const int slot0 = (wv * 4 + it) * 64;          // wave-uniform LDS slot
    const int f     = slot0 + lane;                // 0..1023
    const f16x8* src = &Xh[(size_t)(b0b + (f >> 6)) * 64 + (f & 63)];
    __builtin_amdgcn_global_load_lds(
        (const __attribute__((address_space(1))) void*)src,
        (__attribute__((address_space(3))) void*)&Xs[slot0],
        16, 0, 0);
  }
  __syncthreads();   // drains vmcnt; only barrier in the kernel

  const _Float16 hinf = (_Float16)__builtin_inff();
  h2 acc2[MB][NO];
#pragma unroll
  for (int m = 0; m < MB; ++m)
#pragma unroll
    for (int n = 0; n < NO; ++n) acc2[m][n] = (h2){hinf, hinf};

#pragma unroll
  for (int c = 0; c < 4; ++c) {                    // 4 chunks of 128 k
    const int slot = c * 16 + k16;
    f16x8 x8[MB];
#pragma unroll
    for (int m = 0; m < MB; ++m)
      x8[m] = Xs[(bw + m) * 64 + slot];            // ds_read_b128, broadcast
#pragma unroll
    for (int n = 0; n < NO; ++n) {
      const f16x8 w8 = Wh[(size_t)(o0 + n * 4 + og) * 64 + slot];  // L1
      const h2 w0 = pair_of<0>(w8), w1 = pair_of<1>(w8),
               w2 = pair_of<2>(w8), w3 = pair_of<3>(w8);
#pragma unroll
      for (int m = 0; m < MB; ++m) {
        const h2 s0 = pair_of<0>(x8[m]) + w0;      // v_pk_add_f16
        acc2[m][n] = pkmin(acc2[m][n], s0);        // v_pk_min_f16
        const h2 s1 = pair_of<1>(x8[m]) + w1;
        acc2[m][n] = pkmin(acc2[m][n], s1);
        const h2 s2 = pair_of<2>(x8[m]) + w2;
        acc2[m][n] = pkmin(acc2[m][n], s2);
        const h2 s3 = pair_of<3>(x8[m]) + w3;
        acc2[m][n] = pkmin(acc2[m][n], s3);
      }
    }
  }

  // ---- pair-reduce to f32, then compacting butterfly over k16 bits ----
  float v0[32];
#pragma unroll
  for (int m = 0; m < MB; ++m)
#pragma unroll
    for (int n = 0; n < NO; ++n)
      v0[(m << 2) | n] = fminf((float)acc2[m][n][0], (float)acc2[m][n][1]);

  const bool bb0 = (k16 & 1);
  float v1[16];
#pragma unroll
  for (int i = 0; i < 16; ++i) {
    float keep = bb0 ? v0[2 * i + 1] : v0[2 * i];
    float send = bb0 ? v0[2 * i]     : v0[2 * i + 1];
    v1[i] = fminf(keep, __shfl_xor(send, 1, 64));
  }
  const bool bb1 = (k16 >> 1) & 1;
  float v2[8];
#pragma unroll
  for (int i = 0; i < 8; ++i) {
    float keep = bb1 ? v1[2 * i + 1] : v1[2 * i];
    float send = bb1 ? v1[2 * i]     : v1[2 * i + 1];
    v2[i] = fminf(keep, __shfl_xor(send, 2, 64));
  }
  const bool bb2 = (k16 >> 2) & 1;
  float v3[4];
#pragma unroll
  for (int i = 0; i < 4; ++i) {
    float keep = bb2 ? v2[2 * i + 1] : v2[2 * i];
    float send = bb2 ? v2[2 * i]     : v2[2 * i + 1];
    v3[i] = fminf(keep, __shfl_xor(send, 4, 64));
  }
  const bool bb3 = (k16 >> 3) & 1;
  float v4[2];
#pragma unroll
  for (int i = 0; i < 2; ++i) {
    float keep = bb3 ? v3[2 * i + 1] : v3[2 * i];
    float send = bb3 ? v3[2 * i]     : v3[2 * i + 1];
    v4[i] = fminf(keep, __shfl_xor(send, 8, 64));
  }

  // lane holds items j = k16 + 16*h  ->  m = (k16>>2) + 4h, n = k16&3
  const int mrow = k16 >> 2;
  const int ncol = k16 & 3;
#pragma unroll
  for (int h = 0; h < 2; ++h) {
    out[(size_t)(b0b + bw + 4 * h + mrow) * O_F + o0 + 4 * ncol + og] = v4[h];
  }
}

extern "C" void kernel_launch(void* const* d_in, const int* in_sizes, int n_in,
                              void* d_out, int out_size, void* d_ws, size_t ws_size,
                              hipStream_t stream) {
  const float* X = (const float*)d_in[0];
  const float* W = (const float*)d_in[1];
  float* out     = (float*)d_out;

  f16x8* Xh = (f16x8*)d_ws;            // XN/8 = 65536 slots
  f16x8* Wh = Xh + XN / 8;             // WN/8 = 32768 slots

  hipLaunchKernelGGL(cvt_f16, dim3((XN + WN) / 8 / NTHR), dim3(NTHR), 0,
                     stream, X, W, Xh);
  hipLaunchKernelGGL(tropical_v9, dim3(1024), dim3(NTHR), 0, stream,
                     Xh, Wh, out);
}

// Round 11
// 23.721 us; speedup vs baseline: 1.0306x; 1.0306x over previous
//
#include <hip/hip_runtime.h>
#include <math.h>

// Tropical (min-plus) linear: out[b,o] = min_i(X[b,i] + W[o,i])
// B=1024, I=512, O=512 fp32 in/out. Pure-VALU problem (no min-plus MFMA).
//
// Round-11 == round-10 with the cvt_pkrtz type fix (plain _Float16 casts;
// the compiler forms packed converts itself).
//  - Pre-pass converts ONLY W -> fp16 (0.5 MB) into d_ws.
//  - X converted inline during the once-per-block LDS staging:
//    global f32x4 loads -> f16 casts -> ds_write_b128 (16 KB tile).
//  - Main loop: v_pk_add_f16 + v_pk_min_f16 = 1.0 VALU inst/candidate;
//    fp16 LDS reads, fp16 W stream from L1.
//  - lane = (og[2], k16[4]); acc 8b x 4o half2; pair-reduce to f32; 4-step
//    compacting butterfly min over k16; 2 outputs/thread.
//  - Grid 1024 blocks (16 b x 32 o), XCD-swizzled, 4 waves/SIMD.
//  - absmax budget 9.06e-2; fp16 rounding gives ~3e-2. OK.

#define B_SZ  1024
#define O_F   512
#define I_F   512
#define MB    8      // b rows per thread (and per wave)
#define NO    4      // o per thread (wave covers 16 o)
#define NTHR  256
#define WN    (O_F * I_F)    // 262144 W elems

typedef __attribute__((ext_vector_type(4))) float    f32x4;
typedef __attribute__((ext_vector_type(8))) _Float16 f16x8;
typedef __attribute__((ext_vector_type(2))) _Float16 h2;

template <int J>
static __device__ __forceinline__ h2 pair_of(f16x8 v) {
  return __builtin_shufflevector(v, v, 2 * J, 2 * J + 1);
}

static __device__ __forceinline__ h2 pkmin(h2 a, h2 b) {
  h2 r;
  asm("v_pk_min_f16 %0, %1, %2" : "=v"(r) : "v"(a), "v"(b));
  return r;
}

// ---- pre-pass: convert W only ----
__global__ __launch_bounds__(NTHR, 8)
void cvt_w(const float* __restrict__ W, f16x8* __restrict__ dst) {
  const int t = blockIdx.x * NTHR + threadIdx.x;   // < WN/8 = 32768
  const f32x4* __restrict__ Wv = reinterpret_cast<const f32x4*>(W);
  const f32x4 a = Wv[2 * t];
  const f32x4 b = Wv[2 * t + 1];
  f16x8 h;
  h[0] = (_Float16)a.x; h[1] = (_Float16)a.y;
  h[2] = (_Float16)a.z; h[3] = (_Float16)a.w;
  h[4] = (_Float16)b.x; h[5] = (_Float16)b.y;
  h[6] = (_Float16)b.z; h[7] = (_Float16)b.w;
  dst[t] = h;
}

// ---- main kernel ----
__global__ __launch_bounds__(NTHR, 4)
void tropical_v11(const float* __restrict__ X,    // fp32 [B][512]
                  const f16x8* __restrict__ Wh,   // fp16 [O][64] f16x8
                  float* __restrict__ out) {
  __shared__ f16x8 Xs[16 * 64];   // 16 KB: [b(16)][slot(64)]

  const int tid  = threadIdx.x;
  const int wv   = tid >> 6;
  const int lane = tid & 63;
  const int k16  = lane & 15;   // slot position within 16-lane group
  const int og   = lane >> 4;   // o subgroup 0..3

  // Block tile: 16 b x 32 o; b varies fastest within an XCD (W-panel L2 reuse).
  const int bid = blockIdx.x;
  const int swz = (bid & 7) * 128 + (bid >> 3);   // bijective, 1024 % 8 == 0
  const int ot  = swz >> 6;                       // 16 o-tiles of 32
  const int bt  = swz & 63;                       // 64 b-tiles of 16
  const int b0b = bt * 16;                        // block b base
  const int o0  = ot * 32 + (wv & 1) * 16;        // wave o base
  const int bw  = (wv >> 1) * MB;                 // wave b offset in tile

  const f32x4* __restrict__ Xv = reinterpret_cast<const f32x4*>(X);

  // ---- stage X tile once, converting fp32 -> fp16 in registers ----
  // 1024 f16x8 slots; thread handles 4 slots (f = it*256 + tid).
#pragma unroll
  for (int it = 0; it < 4; ++it) {
    const int f   = it * NTHR + tid;              // 0..1023
    const int row = f >> 6;                       // b row in tile
    const int col = f & 63;                       // f16x8 slot in row
    const f32x4 a = Xv[(size_t)(b0b + row) * 128 + 2 * col];
    const f32x4 b = Xv[(size_t)(b0b + row) * 128 + 2 * col + 1];
    f16x8 h;
    h[0] = (_Float16)a.x; h[1] = (_Float16)a.y;
    h[2] = (_Float16)a.z; h[3] = (_Float16)a.w;
    h[4] = (_Float16)b.x; h[5] = (_Float16)b.y;
    h[6] = (_Float16)b.z; h[7] = (_Float16)b.w;
    Xs[f] = h;                                    // ds_write_b128, no conflict
  }
  __syncthreads();   // only barrier in the kernel

  const _Float16 hinf = (_Float16)__builtin_inff();
  h2 acc2[MB][NO];
#pragma unroll
  for (int m = 0; m < MB; ++m)
#pragma unroll
    for (int n = 0; n < NO; ++n) acc2[m][n] = (h2){hinf, hinf};

#pragma unroll
  for (int c = 0; c < 4; ++c) {                    // 4 chunks of 128 k
    const int slot = c * 16 + k16;
    f16x8 x8[MB];
#pragma unroll
    for (int m = 0; m < MB; ++m)
      x8[m] = Xs[(bw + m) * 64 + slot];            // ds_read_b128, broadcast
#pragma unroll
    for (int n = 0; n < NO; ++n) {
      const f16x8 w8 = Wh[(size_t)(o0 + n * 4 + og) * 64 + slot];  // L1 fp16
      const h2 w0 = pair_of<0>(w8), w1 = pair_of<1>(w8),
               w2 = pair_of<2>(w8), w3 = pair_of<3>(w8);
#pragma unroll
      for (int m = 0; m < MB; ++m) {
        const h2 s0 = pair_of<0>(x8[m]) + w0;      // v_pk_add_f16
        acc2[m][n] = pkmin(acc2[m][n], s0);        // v_pk_min_f16
        const h2 s1 = pair_of<1>(x8[m]) + w1;
        acc2[m][n] = pkmin(acc2[m][n], s1);
        const h2 s2 = pair_of<2>(x8[m]) + w2;
        acc2[m][n] = pkmin(acc2[m][n], s2);
        const h2 s3 = pair_of<3>(x8[m]) + w3;
        acc2[m][n] = pkmin(acc2[m][n], s3);
      }
    }
  }

  // ---- pair-reduce to f32, then compacting butterfly over k16 bits ----
  float v0[32];
#pragma unroll
  for (int m = 0; m < MB; ++m)
#pragma unroll
    for (int n = 0; n < NO; ++n)
      v0[(m << 2) | n] = fminf((float)acc2[m][n][0], (float)acc2[m][n][1]);

  const bool bb0 = (k16 & 1);
  float v1[16];
#pragma unroll
  for (int i = 0; i < 16; ++i) {
    float keep = bb0 ? v0[2 * i + 1] : v0[2 * i];
    float send = bb0 ? v0[2 * i]     : v0[2 * i + 1];
    v1[i] = fminf(keep, __shfl_xor(send, 1, 64));
  }
  const bool bb1 = (k16 >> 1) & 1;
  float v2[8];
#pragma unroll
  for (int i = 0; i < 8; ++i) {
    float keep = bb1 ? v1[2 * i + 1] : v1[2 * i];
    float send = bb1 ? v1[2 * i]     : v1[2 * i + 1];
    v2[i] = fminf(keep, __shfl_xor(send, 2, 64));
  }
  const bool bb2 = (k16 >> 2) & 1;
  float v3[4];
#pragma unroll
  for (int i = 0; i < 4; ++i) {
    float keep = bb2 ? v2[2 * i + 1] : v2[2 * i];
    float send = bb2 ? v2[2 * i]     : v2[2 * i + 1];
    v3[i] = fminf(keep, __shfl_xor(send, 4, 64));
  }
  const bool bb3 = (k16 >> 3) & 1;
  float v4[2];
#pragma unroll
  for (int i = 0; i < 2; ++i) {
    float keep = bb3 ? v3[2 * i + 1] : v3[2 * i];
    float send = bb3 ? v3[2 * i]     : v3[2 * i + 1];
    v4[i] = fminf(keep, __shfl_xor(send, 8, 64));
  }

  // lane holds items j = k16 + 16*h  ->  m = (k16>>2) + 4h, n = k16&3
  const int mrow = k16 >> 2;
  const int ncol = k16 & 3;
#pragma unroll
  for (int h = 0; h < 2; ++h) {
    out[(size_t)(b0b + bw + 4 * h + mrow) * O_F + o0 + 4 * ncol + og] = v4[h];
  }
}

extern "C" void kernel_launch(void* const* d_in, const int* in_sizes, int n_in,
                              void* d_out, int out_size, void* d_ws, size_t ws_size,
                              hipStream_t stream) {
  const float* X = (const float*)d_in[0];
  const float* W = (const float*)d_in[1];
  float* out     = (float*)d_out;

  f16x8* Wh = (f16x8*)d_ws;   // WN/8 = 32768 slots (0.5 MB)

  hipLaunchKernelGGL(cvt_w, dim3(WN / 8 / NTHR), dim3(NTHR), 0, stream, W, Wh);
  hipLaunchKernelGGL(tropical_v11, dim3(1024), dim3(NTHR), 0, stream,
                     X, Wh, out);
}

// Round 12
// 17.845 us; speedup vs baseline: 1.3699x; 1.3293x over previous
//
#include <hip/hip_runtime.h>
#include <math.h>

// Tropical (min-plus) linear: out[b,o] = min_i(X[b,i] + W[o,i])
// B=1024, I=512, O=512 fp32 in/out. Pure-VALU problem (no min-plus MFMA).
//
// Round-12: SINGLE-KERNEL fp16 (v11 showed the 2-kernel structure cost ~6us).
//  - Block tile 32b x 32o, 256 threads (4 waves), grid 512 = 2 blocks/CU.
//  - Both X and W tiles converted fp32->fp16 in registers during one-time
//    staging into LDS (Xs 32KB + Ws 32KB = 64KB). No pre-pass kernel.
//  - Main loop: per thread MB=8 x NO=8 accs; per chunk 16 ds_read_b128 feed
//    512 packed VALU (v_pk_add_f16 + v_pk_min_f16 = 1.0 inst/candidate).
//  - W LDS cols XOR-swizzled (col ^ ((row&3)<<1)) so the 4 og-rows hit
//    distinct bank quads; 16-lane groups read contiguous 256B -> conflict-free.
//  - Packed butterfly: h2 pkmin + 32-bit shfl_xor over k16 bits, unpack at
//    the last step; 4 outputs/thread.
//  - absmax budget 9.06e-2; fp16 rounding ~3e-2. OK (v11 measured 0.031).

#define B_SZ 1024
#define O_F  512
#define I_F  512
#define NTHR 256
#define MBT  8    // b rows per thread
#define NN   8    // o cols per thread (x4 og-groups = 32 o per wave)

typedef __attribute__((ext_vector_type(4))) float    f32x4;
typedef __attribute__((ext_vector_type(8))) _Float16 f16x8;
typedef __attribute__((ext_vector_type(2))) _Float16 h2;

template <int J>
static __device__ __forceinline__ h2 pair_of(f16x8 v) {
  return __builtin_shufflevector(v, v, 2 * J, 2 * J + 1);
}

static __device__ __forceinline__ h2 pkmin(h2 a, h2 b) {
  h2 r;
  asm("v_pk_min_f16 %0, %1, %2" : "=v"(r) : "v"(a), "v"(b));
  return r;
}

static __device__ __forceinline__ h2 shfl_xor_h2(h2 v, int mask) {
  float f = __builtin_bit_cast(float, v);
  f = __shfl_xor(f, mask, 64);
  return __builtin_bit_cast(h2, f);
}

static __device__ __forceinline__ f16x8 cvt8(f32x4 a, f32x4 b) {
  f16x8 h;
  h[0] = (_Float16)a.x; h[1] = (_Float16)a.y;
  h[2] = (_Float16)a.z; h[3] = (_Float16)a.w;
  h[4] = (_Float16)b.x; h[5] = (_Float16)b.y;
  h[6] = (_Float16)b.z; h[7] = (_Float16)b.w;
  return h;
}

__global__ __launch_bounds__(NTHR, 2)
void tropical_v12(const float* __restrict__ X,
                  const float* __restrict__ W,
                  float* __restrict__ out) {
  __shared__ f16x8 Xs[32 * 64];   // 32 KB: [b row][col^swz]
  __shared__ f16x8 Ws[32 * 64];   // 32 KB: [o row][col^swz]

  const int tid  = threadIdx.x;
  const int wv   = tid >> 6;
  const int lane = tid & 63;
  const int k16  = lane & 15;   // k-slot position within 16-lane group
  const int og   = lane >> 4;   // o subgroup 0..3

  // 512 blocks = 32 b-tiles x 16 o-tiles; b varies fastest within an XCD.
  const int bid = blockIdx.x;
  const int swz = (bid & 7) * 64 + (bid >> 3);    // bijective, 512 % 8 == 0
  const int bt  = swz & 31;
  const int ot  = swz >> 5;
  const int b0b = bt * 32;
  const int o0b = ot * 32;
  const int bw  = wv * MBT;     // wave b offset in tile

  const f32x4* __restrict__ Xv = reinterpret_cast<const f32x4*>(X);
  const f32x4* __restrict__ Wv = reinterpret_cast<const f32x4*>(W);

  // ---- stage X and W tiles once, fp32 -> fp16 in registers ----
  // 2048 slots each; thread handles 8 slots per tile.
#pragma unroll
  for (int it = 0; it < 8; ++it) {
    const int f    = it * NTHR + tid;             // 0..2047
    const int row  = f >> 6;                      // 0..31
    const int col  = f & 63;
    const int colp = col ^ ((row & 3) << 1);      // bank-spread swizzle
    const f32x4 a = Xv[(size_t)(b0b + row) * 128 + 2 * col];
    const f32x4 b = Xv[(size_t)(b0b + row) * 128 + 2 * col + 1];
    Xs[row * 64 + colp] = cvt8(a, b);             // ds_write_b128
  }
#pragma unroll
  for (int it = 0; it < 8; ++it) {
    const int f    = it * NTHR + tid;
    const int row  = f >> 6;
    const int col  = f & 63;
    const int colp = col ^ ((row & 3) << 1);
    const f32x4 a = Wv[(size_t)(o0b + row) * 128 + 2 * col];
    const f32x4 b = Wv[(size_t)(o0b + row) * 128 + 2 * col + 1];
    Ws[row * 64 + colp] = cvt8(a, b);
  }
  __syncthreads();   // only barrier in the kernel

  const _Float16 hinf = (_Float16)__builtin_inff();
  h2 acc2[MBT][NN];
#pragma unroll
  for (int m = 0; m < MBT; ++m)
#pragma unroll
    for (int n = 0; n < NN; ++n) acc2[m][n] = (h2){hinf, hinf};

#pragma unroll
  for (int c = 0; c < 4; ++c) {                    // 4 chunks of 128 k
    const int slot = c * 16 + k16;
    f16x8 x8[MBT];
#pragma unroll
    for (int m = 0; m < MBT; ++m) {
      const int row = bw + m;
      x8[m] = Xs[row * 64 + (slot ^ ((row & 3) << 1))];  // broadcast b128
    }
#pragma unroll
    for (int n = 0; n < NN; ++n) {
      const int row = n * 4 + og;
      const f16x8 w8 = Ws[row * 64 + (slot ^ ((row & 3) << 1))];
      const h2 w0 = pair_of<0>(w8), w1 = pair_of<1>(w8),
               w2 = pair_of<2>(w8), w3 = pair_of<3>(w8);
#pragma unroll
      for (int m = 0; m < MBT; ++m) {
        acc2[m][n] = pkmin(acc2[m][n], pair_of<0>(x8[m]) + w0);
        acc2[m][n] = pkmin(acc2[m][n], pair_of<1>(x8[m]) + w1);
        acc2[m][n] = pkmin(acc2[m][n], pair_of<2>(x8[m]) + w2);
        acc2[m][n] = pkmin(acc2[m][n], pair_of<3>(x8[m]) + w3);
      }
    }
  }

  // ---- packed compacting butterfly min over lane bits 0..3 (k16) ----
  // items j = (m<<3)|n, 64 h2 values; step s fixes j-bit s == lane-bit s.
  h2 v0[64];
#pragma unroll
  for (int m = 0; m < MBT; ++m)
#pragma unroll
    for (int n = 0; n < NN; ++n) v0[(m << 3) | n] = acc2[m][n];

  const bool bb0 = (k16 & 1);
  h2 v1[32];
#pragma unroll
  for (int i = 0; i < 32; ++i) {
    h2 keep = bb0 ? v0[2 * i + 1] : v0[2 * i];
    h2 send = bb0 ? v0[2 * i]     : v0[2 * i + 1];
    v1[i] = pkmin(keep, shfl_xor_h2(send, 1));
  }
  const bool bb1 = (k16 >> 1) & 1;
  h2 v2[16];
#pragma unroll
  for (int i = 0; i < 16; ++i) {
    h2 keep = bb1 ? v1[2 * i + 1] : v1[2 * i];
    h2 send = bb1 ? v1[2 * i]     : v1[2 * i + 1];
    v2[i] = pkmin(keep, shfl_xor_h2(send, 2));
  }
  const bool bb2 = (k16 >> 2) & 1;
  h2 v3[8];
#pragma unroll
  for (int i = 0; i < 8; ++i) {
    h2 keep = bb2 ? v2[2 * i + 1] : v2[2 * i];
    h2 send = bb2 ? v2[2 * i]     : v2[2 * i + 1];
    v3[i] = pkmin(keep, shfl_xor_h2(send, 4));
  }
  const bool bb3 = (k16 >> 3) & 1;
  h2 v4[4];
#pragma unroll
  for (int i = 0; i < 4; ++i) {
    h2 keep = bb3 ? v3[2 * i + 1] : v3[2 * i];
    h2 send = bb3 ? v3[2 * i]     : v3[2 * i + 1];
    v4[i] = pkmin(keep, shfl_xor_h2(send, 8));
  }

  // lane holds items j = k16 + 16*h (h=0..3) -> m = j>>3, n = j&7
#pragma unroll
  for (int h = 0; h < 4; ++h) {
    const int j = k16 + 16 * h;
    const int m = j >> 3;
    const int n = j & 7;
    const float r = fminf((float)v4[h][0], (float)v4[h][1]);
    out[(size_t)(b0b + bw + m) * O_F + o0b + n * 4 + og] = r;
  }
}

extern "C" void kernel_launch(void* const* d_in, const int* in_sizes, int n_in,
                              void* d_out, int out_size, void* d_ws, size_t ws_size,
                              hipStream_t stream) {
  const float* X = (const float*)d_in[0];
  const float* W = (const float*)d_in[1];
  float* out     = (float*)d_out;

  hipLaunchKernelGGL(tropical_v12, dim3(512), dim3(NTHR), 0, stream,
                     X, W, out);
}

// Round 14
// 17.762 us; speedup vs baseline: 1.3763x; 1.0047x over previous
//
#include <hip/hip_runtime.h>
#include <math.h>

// Tropical (min-plus) linear: out[b,o] = min_i(X[b,i] + W[o,i])
// B=1024, I=512, O=512 fp32. Pure-VALU problem (no min-plus MFMA).
//
// FINAL (= round-7, best measured: 17.80 us, absmax 0.0).
//  - K-on-lanes: lane = (og[2], k16[4]); k collapses inside the wave ->
//    single kernel, no workspace, no second graph node (+6us/node measured).
//  - Split operand pipes: X tile (8b x 512k = 16 KB) staged in LDS once via
//    global_load_lds (one barrier total); in-loop X reads are broadcast
//    ds_read_b128 (lgkm pipe). W streams per-lane coalesced from L1 (vm pipe).
//  - Per thread per 4k: 4 LDS + 4 L1 b128 insts feed 96 VALU
//    (v_add_f32 + v_min3_f32), 16 independent acc chains.
//  - Occupancy: 2048 blocks (8 blocks/CU), __launch_bounds__(256, 8).
//  - 4-step compacting butterfly min over k16 bits -> 1 output/thread.
//  - Wall-time decomposition (rounds 5/6/7/12): ~17.8 us is harness/launch
//    floor dominated; device portion is near the VALU issue floor. fp16 and
//    packed-fp32 variants measured identical-or-worse wall.

#define B_SZ  1024
#define O_F   512
#define I_F   512
#define MB    4      // b rows per thread (and per wave)
#define NO    4      // o per thread (wave covers 16 o)
#define NTHR  256

typedef __attribute__((ext_vector_type(4))) float f32x4;

__global__ __launch_bounds__(NTHR, 8)
void tropical_v7(const float* __restrict__ X,
                 const float* __restrict__ W,
                 float* __restrict__ out) {
  __shared__ f32x4 Xs[8 * 128];   // 16 KB: [b(8)][k4(128)] linear

  const int tid  = threadIdx.x;
  const int wv   = tid >> 6;
  const int lane = tid & 63;
  const int k16  = lane & 15;   // k4 position within 16-lane group
  const int og   = lane >> 4;   // o subgroup 0..3

  // Block tile: 8 b x 32 o. 2048 tiles: 128 b-tiles x 16 o-tiles.
  // XCD swizzle (bijective, 2048 % 8 == 0): b varies fastest per XCD chunk.
  const int bid = blockIdx.x;
  const int swz = (bid & 7) * 256 + (bid >> 3);
  const int ot  = swz >> 7;                       // 16 o-tiles of 32
  const int bt  = swz & 127;                      // 128 b-tiles of 8
  const int b0b = bt * 8;                         // block b base
  const int o0  = ot * 32 + (wv & 1) * 16;        // wave o base
  const int bw  = (wv >> 1) * MB;                 // wave b offset in tile

  const f32x4* __restrict__ Xv = reinterpret_cast<const f32x4*>(X);
  const f32x4* __restrict__ Wv = reinterpret_cast<const f32x4*>(W);
  const int R4 = I_F / 4;   // 128 float4 per row

  // ---- stage X tile once: 1024 float4 = 4 rounds x 256 lanes ----
#pragma unroll
  for (int it = 0; it < 4; ++it) {
    const int slot0 = (wv * 4 + it) * 64;          // wave-uniform LDS slot
    const int f     = slot0 + lane;                // 0..1023
    const f32x4* src = &Xv[(size_t)(b0b + (f >> 7)) * R4 + (f & 127)];
    __builtin_amdgcn_global_load_lds(
        (const __attribute__((address_space(1))) void*)src,
        (__attribute__((address_space(3))) void*)&Xs[slot0],
        16, 0, 0);
  }
  __syncthreads();   // drains vmcnt; only barrier in the kernel

  float acc[MB][NO];
#pragma unroll
  for (int m = 0; m < MB; ++m)
#pragma unroll
    for (int n = 0; n < NO; ++n) acc[m][n] = __builtin_inff();

#pragma unroll
  for (int c = 0; c < I_F / 64; ++c) {             // 8 chunks of 64 k
    const int k4 = c * 16 + k16;
    f32x4 x4[MB];
#pragma unroll
    for (int m = 0; m < MB; ++m)
      x4[m] = Xs[(bw + m) * 128 + k4];             // ds_read_b128, broadcast
#pragma unroll
    for (int n = 0; n < NO; ++n) {
      const f32x4 w4 = Wv[(size_t)(o0 + n * 4 + og) * R4 + k4];  // L1, unique
#pragma unroll
      for (int m = 0; m < MB; ++m) {
        float c0 = x4[m].x + w4.x;
        float c1 = x4[m].y + w4.y;
        float c2 = x4[m].z + w4.z;
        float c3 = x4[m].w + w4.w;
        acc[m][n] = fminf(fminf(c0, c1), acc[m][n]);   // v_min3_f32
        acc[m][n] = fminf(fminf(c2, c3), acc[m][n]);   // v_min3_f32
      }
    }
  }

  // ---- compacting butterfly min-reduce over lane bits 0..3 (k16) ----
  // items j = (m<<2)|n ; step s fixes j-bit s == lane-bit s.
  float v0[16];
#pragma unroll
  for (int m = 0; m < MB; ++m)
#pragma unroll
    for (int n = 0; n < NO; ++n) v0[(m << 2) | n] = acc[m][n];

  const bool bb0 = (k16 & 1);
  float v1[8];
#pragma unroll
  for (int i = 0; i < 8; ++i) {
    float keep = bb0 ? v0[2 * i + 1] : v0[2 * i];
    float send = bb0 ? v0[2 * i]     : v0[2 * i + 1];
    v1[i] = fminf(keep, __shfl_xor(send, 1, 64));
  }
  const bool bb1 = (k16 >> 1) & 1;
  float v2[4];
#pragma unroll
  for (int i = 0; i < 4; ++i) {
    float keep = bb1 ? v1[2 * i + 1] : v1[2 * i];
    float send = bb1 ? v1[2 * i]     : v1[2 * i + 1];
    v2[i] = fminf(keep, __shfl_xor(send, 2, 64));
  }
  const bool bb2 = (k16 >> 2) & 1;
  float v3[2];
#pragma unroll
  for (int i = 0; i < 2; ++i) {
    float keep = bb2 ? v2[2 * i + 1] : v2[2 * i];
    float send = bb2 ? v2[2 * i]     : v2[2 * i + 1];
    v3[i] = fminf(keep, __shfl_xor(send, 4, 64));
  }
  const bool bb3 = (k16 >> 3) & 1;
  {
    float keep = bb3 ? v3[1] : v3[0];
    float send = bb3 ? v3[0] : v3[1];
    const float r = fminf(keep, __shfl_xor(send, 8, 64));
    // lane holds item j = k16 -> m = k16>>2, n = k16&3
    const int mrow = k16 >> 2;
    const int ncol = k16 & 3;
    out[(size_t)(b0b + bw + mrow) * O_F + o0 + 4 * ncol + og] = r;
  }
}

extern "C" void kernel_launch(void* const* d_in, const int* in_sizes, int n_in,
                              void* d_out, int out_size, void* d_ws, size_t ws_size,
                              hipStream_t stream) {
  const float* X = (const float*)d_in[0];
  const float* W = (const float*)d_in[1];
  float* out     = (float*)d_out;

  hipLaunchKernelGGL(tropical_v7, dim3(2048), dim3(NTHR), 0, stream,
                     X, W, out);
}